// Round 6
// baseline (335.248 us; speedup 1.0000x reference)
//
#include <hip/hip_runtime.h>
#include <hip/hip_bf16.h>
#include <math.h>

// MaxAggregator: N=100000 nodes, E=1600000 edges, D=64, fp32.
// d_in[0]=x [N,64], d_in[1]=W [64,64], d_in[2]=b [64], d_in[3]=edge_index [2,E] i32
//
// Pipeline (round 2 design; resubmitted — four acquisition timeouts, never measured):
//   memset deg=0
//   K1 bin_edges  : slot=atomicAdd(deg[r]); bins[slot*N + r]=c   (COLUMN-major:
//                   hot slot regions are dense -> 64B lines collect ~16 writes
//                   while cache-resident instead of 1; kills write amplification)
//   K2 agg_linear : fused. 64 nodes/block; wave-per-node gather-max into LDS
//                   tile, then 64x64 linear from LDS (W^T staged in LDS).

#define CAP 64   // max tracked degree; P(exceed) ~ 2e-13 for E/N=16 random edges

__global__ __launch_bounds__(256) void bin_edges_kernel(
    const int* __restrict__ ei, int* __restrict__ bins,
    int* __restrict__ deg, int E, int N) {
  int e = blockIdx.x * blockDim.x + threadIdx.x;
  if (e >= E) return;
  int r = ei[e];        // destination node
  int c = ei[E + e];    // source node
  int slot = atomicAdd(&deg[r], 1);
  if (slot < CAP) bins[slot * N + r] = c;
}

// Fused scatter-max aggregation + linear layer.
// Phase 1: wave w aggregates nodes [base+16w, base+16w+16); lane = feature dim.
//          Each neighbor gather = one coalesced 256B row read (L2/L3-hit).
// Phase 2: out[64 nodes][64 outs] = Agg @ W^T + b, 4x4 register microtile.
__global__ __launch_bounds__(256) void agg_linear_kernel(
    const float* __restrict__ x, const int* __restrict__ bins,
    const int* __restrict__ deg, const float* __restrict__ W,
    const float* __restrict__ bias, float* __restrict__ out, int N) {
  __shared__ float Agg[64][65];   // +1 pad: phase-2 reads hit 4 distinct banks
  __shared__ float Wt[64 * 68];   // Wt[k*68+o] = W[o][k]; 68 keeps float4 aligned

  int t = threadIdx.x;
  for (int idx = t; idx < 4096; idx += 256) {
    int o = idx >> 6, k = idx & 63;
    Wt[k * 68 + o] = W[idx];
  }

  int base = blockIdx.x * 64;
  int w    = t >> 6;    // wave id 0..3
  int lane = t & 63;    // feature dim

  // ---- Phase 1: aggregate 16 nodes per wave ----
  for (int i = 0; i < 16; ++i) {
    int node = base + w * 16 + i;
    float m;
    if (node < N) {
      int d = deg[node];
      d = d < CAP ? d : CAP;
      if (d == 0) {
        m = x[node * 64 + lane];           // isolated node keeps own feature
      } else {
        m = -INFINITY;
        const int* bp = bins + node;       // column-major: entry s at bp[s*N]
        int s = 0;
        for (; s + 8 <= d; s += 8) {       // 8 gathers in flight (latency cover)
          int c0 = bp[(s + 0) * N];
          int c1 = bp[(s + 1) * N];
          int c2 = bp[(s + 2) * N];
          int c3 = bp[(s + 3) * N];
          int c4 = bp[(s + 4) * N];
          int c5 = bp[(s + 5) * N];
          int c6 = bp[(s + 6) * N];
          int c7 = bp[(s + 7) * N];
          float v0 = x[c0 * 64 + lane];
          float v1 = x[c1 * 64 + lane];
          float v2 = x[c2 * 64 + lane];
          float v3 = x[c3 * 64 + lane];
          float v4 = x[c4 * 64 + lane];
          float v5 = x[c5 * 64 + lane];
          float v6 = x[c6 * 64 + lane];
          float v7 = x[c7 * 64 + lane];
          float a0 = fmaxf(v0, v1), a1 = fmaxf(v2, v3);
          float a2 = fmaxf(v4, v5), a3 = fmaxf(v6, v7);
          m = fmaxf(m, fmaxf(fmaxf(a0, a1), fmaxf(a2, a3)));
        }
        for (; s < d; ++s) {
          int c = bp[s * N];
          m = fmaxf(m, x[c * 64 + lane]);
        }
      }
    } else {
      m = 0.f;   // padded row; never stored (store is guarded) but keeps LDS clean
    }
    Agg[w * 16 + i][lane] = m;
  }
  __syncthreads();

  // ---- Phase 2: linear on the 64-node LDS tile ----
  int to = t & 15;    // output cols 4*to..+3
  int tn = t >> 4;    // local rows 4*tn..+3

  float acc[4][4];
#pragma unroll
  for (int i = 0; i < 4; ++i)
#pragma unroll
    for (int j = 0; j < 4; ++j) acc[i][j] = 0.f;

#pragma unroll 4
  for (int k = 0; k < 64; ++k) {
    float4 wq = *reinterpret_cast<const float4*>(&Wt[k * 68 + 4 * to]);
    float wv[4] = {wq.x, wq.y, wq.z, wq.w};
#pragma unroll
    for (int i = 0; i < 4; ++i) {
      float a = Agg[4 * tn + i][k];
#pragma unroll
      for (int j = 0; j < 4; ++j) acc[i][j] += a * wv[j];
    }
  }

  float4 bq = *reinterpret_cast<const float4*>(&bias[4 * to]);
  float bv[4] = {bq.x, bq.y, bq.z, bq.w};
#pragma unroll
  for (int i = 0; i < 4; ++i) {
    int node = base + 4 * tn + i;
    if (node < N) {
      float4 r;
      r.x = acc[i][0] + bv[0];
      r.y = acc[i][1] + bv[1];
      r.z = acc[i][2] + bv[2];
      r.w = acc[i][3] + bv[3];
      *reinterpret_cast<float4*>(&out[node * 64 + 4 * to]) = r;
    }
  }
}

extern "C" void kernel_launch(void* const* d_in, const int* in_sizes, int n_in,
                              void* d_out, int out_size, void* d_ws, size_t ws_size,
                              hipStream_t stream) {
  const float* x    = (const float*)d_in[0];
  const float* W    = (const float*)d_in[1];
  const float* bias = (const float*)d_in[2];
  const int*   ei   = (const int*)d_in[3];
  float* out = (float*)d_out;

  int N = in_sizes[0] / 64;   // 100000
  int E = in_sizes[3] / 2;    // 1600000

  // Workspace: bins CAP*N ints (25.6 MB) + deg N ints (0.4 MB)
  char* ws = (char*)d_ws;
  int* bins = (int*)ws;
  int* deg  = (int*)(ws + (size_t)CAP * N * 4);

  hipMemsetAsync(deg, 0, (size_t)N * 4, stream);

  {
    int blocks = (E + 255) / 256;
    bin_edges_kernel<<<blocks, 256, 0, stream>>>(ei, bins, deg, E, N);
  }
  {
    int blocks = (N + 63) / 64;
    agg_linear_kernel<<<blocks, 256, 0, stream>>>(x, bins, deg, W, bias, out, N);
  }
}

// Round 9
// 317.818 us; speedup vs baseline: 1.0548x; 1.0548x over previous
//
#include <hip/hip_runtime.h>
#include <hip/hip_bf16.h>
#include <math.h>

// MaxAggregator: N=100000 nodes, E=1600000 edges, D=64, fp32.
// d_in[0]=x [N,64], d_in[1]=W [64,64], d_in[2]=b [64], d_in[3]=edge_index [2,E] i32
//
// Round 8: R7 design + OOB fix. R7 crashed: for node>=N (last block),
// d=__shfl(dvec,i) returned deg[N-1]>0 -> gather path read bins past the
// column end -> 0xAA poison int (negative) -> (size_t)c*64 sign-extended ->
// GPU memory fault. Fix: force d=0 for node>=N (that path guards its x read).
//
//   agg_linear latency-bound fix (R6: dur 150us, occ 34%, VALU 18%):
//   - 512-thread blocks, 128 nodes/block: LDS 49.7KB -> 3 blocks/CU = 24 waves (75%)
//   - degs preloaded per wave (1 load + shfl, was 16 dependent scalar loads)
//   - d>=16 fast path: fixed 16-deep bins->gather batch (2x outstanding vs 8)
// bin_edges deliberately unchanged (needs its own counters this round).

#define CAP 64   // max tracked degree; P(exceed) ~ 2e-13 for E/N=16 random edges

__global__ __launch_bounds__(256) void bin_edges_kernel(
    const int* __restrict__ ei, int* __restrict__ bins,
    int* __restrict__ deg, int E, int N) {
  int e = blockIdx.x * blockDim.x + threadIdx.x;
  if (e >= E) return;
  int r = ei[e];        // destination node
  int c = ei[E + e];    // source node
  int slot = atomicAdd(&deg[r], 1);
  if (slot < CAP) bins[slot * N + r] = c;
}

// Fused scatter-max aggregation + linear layer.
// Phase 1: wave w aggregates nodes [base+16w, base+16w+16); lane = feature dim.
// Phase 2: out[128 nodes][64 outs] = Agg @ W^T + b, 4x4 register microtile.
__global__ __launch_bounds__(512) void agg_linear_kernel(
    const float* __restrict__ x, const int* __restrict__ bins,
    const int* __restrict__ deg, const float* __restrict__ W,
    const float* __restrict__ bias, float* __restrict__ out, int N) {
  __shared__ float Agg[128][65];  // +1 pad: phase-2 row reads land on distinct banks
  __shared__ float Wt[64 * 64];   // Wt[k*64+o] = W[o][k]; b128 reads 2-way = free

  int t = threadIdx.x;
  for (int idx = t; idx < 4096; idx += 512) {
    int o = idx >> 6, k = idx & 63;
    Wt[k * 64 + o] = W[idx];
  }

  int base = blockIdx.x * 128;
  int w    = t >> 6;    // wave id 0..7
  int lane = t & 63;    // feature dim

  int nb = base + w * 16;                 // this wave's first node
  // Preload the wave's 16 degree values (lanes 0..15 carry them).
  int didx = nb + (lane & 15);
  int dvec = deg[didx < N ? didx : (N - 1)];

  // ---- Phase 1: aggregate 16 nodes per wave ----
  for (int i = 0; i < 16; ++i) {
    int node = nb + i;
    int d = __shfl(dvec, i);
    d = d < CAP ? d : CAP;
    if (node >= N) d = 0;                 // OOB node: take the guarded path
    float m;
    const int* bp = bins + node;          // column-major: entry s at bp[s*N]
    if (d >= 16) {
      // 16 independent bins loads, then 16 independent row-gathers in flight.
      int c[16];
#pragma unroll
      for (int s = 0; s < 16; ++s) c[s] = bp[s * N];
      float v[16];
#pragma unroll
      for (int s = 0; s < 16; ++s) v[s] = x[(size_t)c[s] * 64 + lane];
      float a0 = fmaxf(fmaxf(v[0], v[1]),  fmaxf(v[2], v[3]));
      float a1 = fmaxf(fmaxf(v[4], v[5]),  fmaxf(v[6], v[7]));
      float a2 = fmaxf(fmaxf(v[8], v[9]),  fmaxf(v[10], v[11]));
      float a3 = fmaxf(fmaxf(v[12], v[13]), fmaxf(v[14], v[15]));
      m = fmaxf(fmaxf(a0, a1), fmaxf(a2, a3));
      int s = 16;
      for (; s + 4 <= d; s += 4) {
        int c0 = bp[(s + 0) * N];
        int c1 = bp[(s + 1) * N];
        int c2 = bp[(s + 2) * N];
        int c3 = bp[(s + 3) * N];
        float v0 = x[(size_t)c0 * 64 + lane];
        float v1 = x[(size_t)c1 * 64 + lane];
        float v2 = x[(size_t)c2 * 64 + lane];
        float v3 = x[(size_t)c3 * 64 + lane];
        m = fmaxf(m, fmaxf(fmaxf(v0, v1), fmaxf(v2, v3)));
      }
      for (; s < d; ++s) {
        m = fmaxf(m, x[(size_t)bp[s * N] * 64 + lane]);
      }
    } else if (d > 0) {
      m = -INFINITY;
      int s = 0;
      for (; s + 8 <= d; s += 8) {
        int c0 = bp[(s + 0) * N];
        int c1 = bp[(s + 1) * N];
        int c2 = bp[(s + 2) * N];
        int c3 = bp[(s + 3) * N];
        int c4 = bp[(s + 4) * N];
        int c5 = bp[(s + 5) * N];
        int c6 = bp[(s + 6) * N];
        int c7 = bp[(s + 7) * N];
        float v0 = x[(size_t)c0 * 64 + lane];
        float v1 = x[(size_t)c1 * 64 + lane];
        float v2 = x[(size_t)c2 * 64 + lane];
        float v3 = x[(size_t)c3 * 64 + lane];
        float v4 = x[(size_t)c4 * 64 + lane];
        float v5 = x[(size_t)c5 * 64 + lane];
        float v6 = x[(size_t)c6 * 64 + lane];
        float v7 = x[(size_t)c7 * 64 + lane];
        float a0 = fmaxf(v0, v1), a1 = fmaxf(v2, v3);
        float a2 = fmaxf(v4, v5), a3 = fmaxf(v6, v7);
        m = fmaxf(m, fmaxf(fmaxf(a0, a1), fmaxf(a2, a3)));
      }
      for (; s < d; ++s) {
        m = fmaxf(m, x[(size_t)bp[s * N] * 64 + lane]);
      }
    } else {
      // isolated node keeps own feature (guard OOB node in last block)
      m = node < N ? x[(size_t)node * 64 + lane] : 0.f;
    }
    Agg[w * 16 + i][lane] = m;
  }
  __syncthreads();

  // ---- Phase 2: linear on the 128-node LDS tile ----
  int to = t & 15;    // output cols 4*to..+3
  int tn = t >> 4;    // local rows 4*tn..+3 (tn = 0..31)

  float acc[4][4];
#pragma unroll
  for (int i = 0; i < 4; ++i)
#pragma unroll
    for (int j = 0; j < 4; ++j) acc[i][j] = 0.f;

#pragma unroll 4
  for (int k = 0; k < 64; ++k) {
    float4 wq = *reinterpret_cast<const float4*>(&Wt[k * 64 + 4 * to]);
    float wv[4] = {wq.x, wq.y, wq.z, wq.w};
#pragma unroll
    for (int i = 0; i < 4; ++i) {
      float a = Agg[4 * tn + i][k];
#pragma unroll
      for (int j = 0; j < 4; ++j) acc[i][j] += a * wv[j];
    }
  }

  float4 bq = *reinterpret_cast<const float4*>(&bias[4 * to]);
  float bv[4] = {bq.x, bq.y, bq.z, bq.w};
#pragma unroll
  for (int i = 0; i < 4; ++i) {
    int node = base + 4 * tn + i;
    if (node < N) {
      float4 r;
      r.x = acc[i][0] + bv[0];
      r.y = acc[i][1] + bv[1];
      r.z = acc[i][2] + bv[2];
      r.w = acc[i][3] + bv[3];
      *reinterpret_cast<float4*>(&out[node * 64 + 4 * to]) = r;
    }
  }
}

extern "C" void kernel_launch(void* const* d_in, const int* in_sizes, int n_in,
                              void* d_out, int out_size, void* d_ws, size_t ws_size,
                              hipStream_t stream) {
  const float* x    = (const float*)d_in[0];
  const float* W    = (const float*)d_in[1];
  const float* bias = (const float*)d_in[2];
  const int*   ei   = (const int*)d_in[3];
  float* out = (float*)d_out;

  int N = in_sizes[0] / 64;   // 100000
  int E = in_sizes[3] / 2;    // 1600000

  // Workspace: bins CAP*N ints (25.6 MB) + deg N ints (0.4 MB)
  char* ws = (char*)d_ws;
  int* bins = (int*)ws;
  int* deg  = (int*)(ws + (size_t)CAP * N * 4);

  hipMemsetAsync(deg, 0, (size_t)N * 4, stream);

  {
    int blocks = (E + 255) / 256;
    bin_edges_kernel<<<blocks, 256, 0, stream>>>(ei, bins, deg, E, N);
  }
  {
    int blocks = (N + 127) / 128;
    agg_linear_kernel<<<blocks, 512, 0, stream>>>(x, bins, deg, W, bias, out, N);
  }
}

// Round 11
// 202.762 us; speedup vs baseline: 1.6534x; 1.5674x over previous
//
#include <hip/hip_runtime.h>
#include <hip/hip_bf16.h>
#include <math.h>

// MaxAggregator: N=100000 nodes, E=1600000 edges, D=64, fp32.
// d_in[0]=x [N,64], d_in[1]=W [64,64], d_in[2]=b [64], d_in[3]=edge_index [2,E] i32
//
// Round 10 design (resubmitted after acquisition timeout; never measured).
// Kill the bins structure. R9 measured: bin_edges 129us with 105MB
// amplified scatter-writes (64B line per 4B write, structural across 8 XCD L2s)
// AND agg_linear FETCH 194MB of which ~100MB was bins READ amplification
// (bp[s*N] = one 64B line per 4B slot).
// New pipeline:
//   memset bcnt=0 (3KB)
//   K1 partition : edges -> 782 buckets of 128 dest nodes, packed (c<<7)|rlocal.
//                  Dense per-bucket appends (runs ~20-60B) => ~6.4MB payload.
//   K2 agg_linear: 1 block per bucket. 128x64 tile in LDS; scatter-max via LDS
//                  atomicMax on monotonic uint encoding (exact for fp max).
//                  Sentinel enc(-inf) detects isolated nodes (no deg array).
//                  Then decode+fallback in place, 64x64 linear (R6 structure).

#define BN   128      // nodes per bucket
#define CAPB 2432     // slots/bucket: mean 2048 + 8.5 sigma; overflow P ~ 1e-15
#define TS   65       // tile row stride (pad: GEMM A-reads hit distinct banks)
#define SENT 0x007FFFFFu   // encf(-inf)

__device__ __forceinline__ unsigned encf(float f) {
  unsigned u = __float_as_uint(f);
  return (u & 0x80000000u) ? ~u : (u | 0x80000000u);   // monotonic: a<b <=> enc(a)<enc(b)
}
__device__ __forceinline__ float decf(unsigned u) {
  return (u & 0x80000000u) ? __uint_as_float(u ^ 0x80000000u) : __uint_as_float(~u);
}

// K1: partition edges into 128-node destination buckets.
// 256 thr x 16 edges/thr per block. LDS histogram -> one global atomicAdd per
// touched bucket per block -> dense in-bucket append runs.
__global__ __launch_bounds__(256) void partition_kernel(
    const int* __restrict__ ei, unsigned* __restrict__ part,
    int* __restrict__ bcnt, int E, int NB) {
  __shared__ unsigned hist[800];
  __shared__ unsigned base[800];
  __shared__ unsigned cur[800];
  int t = threadIdx.x;
  for (int i = t; i < NB; i += 256) { hist[i] = 0u; cur[i] = 0u; }
  __syncthreads();

  int chunk = blockIdx.x * 4096;
  int r[16];
#pragma unroll
  for (int i = 0; i < 16; ++i) {
    int e = chunk + i * 256 + t;
    int rr = (e < E) ? ei[e] : -1;
    r[i] = rr;
    if (rr >= 0) atomicAdd(&hist[rr >> 7], 1u);
  }
  __syncthreads();
  for (int i = t; i < NB; i += 256) {
    base[i] = (hist[i] > 0u) ? (unsigned)atomicAdd(&bcnt[i], (int)hist[i]) : 0u;
  }
  __syncthreads();
#pragma unroll
  for (int i = 0; i < 16; ++i) {
    int e = chunk + i * 256 + t;
    if (e < E) {
      int rr = r[i];
      int cc = ei[E + e];                       // source node
      int b = rr >> 7;
      unsigned off = base[b] + atomicAdd(&cur[b], 1u);
      if (off < CAPB)
        part[(size_t)b * CAPB + off] = ((unsigned)cc << 7) | (unsigned)(rr & 127);
    }
  }
}

// K2: per-bucket scatter-max (LDS atomics) + fallback + linear.
__global__ __launch_bounds__(512, 6) void agg_linear_kernel(
    const float* __restrict__ x, const unsigned* __restrict__ part,
    const int* __restrict__ bcnt, const float* __restrict__ W,
    const float* __restrict__ bias, float* __restrict__ out, int N) {
  __shared__ unsigned tile[BN * TS];   // 33280 B; float-reused after decode
  __shared__ float Wt[64 * 68];        // 17408 B; Wt[k*68+o] = W[o][k]
  float* tilef = (float*)tile;

  int t = threadIdx.x;
  int w = t >> 6, lane = t & 63;

  for (int i = t; i < BN * TS; i += 512) tile[i] = SENT;
  for (int idx = t; idx < 4096; idx += 512) {
    int o = idx >> 6, k = idx & 63;
    Wt[k * 68 + o] = W[idx];
  }
  __syncthreads();

  int b = blockIdx.x;
  int cnt = bcnt[b];
  if (cnt > CAPB) cnt = CAPB;
  const unsigned* ebase = part + (size_t)b * CAPB;

  // Edge phase: each wave takes 64-edge super-batches, 8 gathers in flight.
  for (int e0 = w * 64; e0 < cnt; e0 += 512) {
    int idx = e0 + lane;
    unsigned pk = (idx < cnt) ? ebase[idx] : 0u;
    int nv = cnt - e0; if (nv > 64) nv = 64;
    for (int j0 = 0; j0 < nv; j0 += 8) {
      unsigned p[8]; float v[8];
#pragma unroll
      for (int jj = 0; jj < 8; ++jj) p[jj] = __shfl(pk, j0 + jj);
#pragma unroll
      for (int jj = 0; jj < 8; ++jj)
        if (j0 + jj < nv) v[jj] = x[(size_t)(p[jj] >> 7) * 64 + lane];
#pragma unroll
      for (int jj = 0; jj < 8; ++jj)
        if (j0 + jj < nv)
          atomicMax(&tile[(p[jj] & 127u) * TS + lane], encf(v[jj]));
    }
  }
  __syncthreads();

  // Fallback + decode in place (each wave owns 16 rows; lane RMWs own slot).
  int basen = b * BN;
#pragma unroll 4
  for (int i = 0; i < 16; ++i) {
    int row = w * 16 + i;
    int node = basen + row;
    unsigned u0 = tile[row * TS];          // broadcast read, dim 0
    unsigned ul = tile[row * TS + lane];
    float val;
    if (u0 == SENT) val = (node < N) ? x[(size_t)node * 64 + lane] : 0.f;
    else            val = decf(ul);
    tilef[row * TS + lane] = val;
  }
  __syncthreads();

  // Linear: out[128 nodes][64 outs] = tile @ W^T + b, 4x4 microtile (R6 order).
  int to = t & 15;    // output cols 4*to..+3
  int tn = t >> 4;    // local rows 4*tn..+3 (0..31)

  float acc[4][4];
#pragma unroll
  for (int i = 0; i < 4; ++i)
#pragma unroll
    for (int j = 0; j < 4; ++j) acc[i][j] = 0.f;

#pragma unroll 4
  for (int k = 0; k < 64; ++k) {
    float4 wq = *reinterpret_cast<const float4*>(&Wt[k * 68 + 4 * to]);
    float wv[4] = {wq.x, wq.y, wq.z, wq.w};
#pragma unroll
    for (int i = 0; i < 4; ++i) {
      float a = tilef[(4 * tn + i) * TS + k];
#pragma unroll
      for (int j = 0; j < 4; ++j) acc[i][j] += a * wv[j];
    }
  }

  float4 bq = *reinterpret_cast<const float4*>(&bias[4 * to]);
  float bv[4] = {bq.x, bq.y, bq.z, bq.w};
#pragma unroll
  for (int i = 0; i < 4; ++i) {
    int node = basen + 4 * tn + i;
    if (node < N) {
      float4 r;
      r.x = acc[i][0] + bv[0];
      r.y = acc[i][1] + bv[1];
      r.z = acc[i][2] + bv[2];
      r.w = acc[i][3] + bv[3];
      *reinterpret_cast<float4*>(&out[(size_t)node * 64 + 4 * to]) = r;
    }
  }
}

extern "C" void kernel_launch(void* const* d_in, const int* in_sizes, int n_in,
                              void* d_out, int out_size, void* d_ws, size_t ws_size,
                              hipStream_t stream) {
  const float* x    = (const float*)d_in[0];
  const float* W    = (const float*)d_in[1];
  const float* bias = (const float*)d_in[2];
  const int*   ei   = (const int*)d_in[3];
  float* out = (float*)d_out;

  int N = in_sizes[0] / 64;   // 100000
  int E = in_sizes[3] / 2;    // 1600000
  int NB = (N + BN - 1) / BN; // 782 buckets

  // Workspace: part NB*CAPB u32 (7.6MB) + bcnt NB ints
  char* ws = (char*)d_ws;
  unsigned* part = (unsigned*)ws;
  int* bcnt = (int*)(ws + (size_t)NB * CAPB * 4);

  hipMemsetAsync(bcnt, 0, (size_t)NB * 4, stream);

  {
    int blocks = (E + 4095) / 4096;
    partition_kernel<<<blocks, 256, 0, stream>>>(ei, part, bcnt, E, NB);
  }
  {
    agg_linear_kernel<<<NB, 512, 0, stream>>>(x, part, bcnt, W, bias, out, N);
  }
}

// Round 16
// 196.012 us; speedup vs baseline: 1.7103x; 1.0344x over previous
//
#include <hip/hip_runtime.h>
#include <hip/hip_bf16.h>
#include <math.h>

// MaxAggregator: N=100000 nodes, E=1600000 edges, D=64, fp32.
// d_in[0]=x [N,64], d_in[1]=W [64,64], d_in[2]=b [64], d_in[3]=edge_index [2,E] i32
//
// Round 12 design (4th resubmit after acquisition timeouts; never measured).
// agg_linear gather widening. R11 measured agg_linear 99.6us with
// occ 38% / VALU 38% / 1.7TB/s => latency-bound on x-row gathers (8 dword
// loads = 2KB in flight per wave). Fix: float4 gathers — one dwordx4 serves
// 4 edges (16-lane groups read 16B each), 16-edge macro-step = 4KB in flight,
// 4x fewer VMEM instructions. partition kernel BYTE-IDENTICAL to R11 so it
// surfaces in top-5 with counters once agg_linear drops below it.

#define BN   128      // nodes per bucket
#define CAPB 2432     // slots/bucket: mean 2048 + 8.5 sigma; overflow P ~ 1e-15
#define TS   65       // tile row stride (pad: GEMM A-reads hit distinct banks)
#define SENT 0x007FFFFFu   // encf(-inf)

__device__ __forceinline__ unsigned encf(float f) {
  unsigned u = __float_as_uint(f);
  return (u & 0x80000000u) ? ~u : (u | 0x80000000u);   // monotonic: a<b <=> enc(a)<enc(b)
}
__device__ __forceinline__ float decf(unsigned u) {
  return (u & 0x80000000u) ? __uint_as_float(u ^ 0x80000000u) : __uint_as_float(~u);
}

// K1: partition edges into 128-node destination buckets. (unchanged from R11)
__global__ __launch_bounds__(256) void partition_kernel(
    const int* __restrict__ ei, unsigned* __restrict__ part,
    int* __restrict__ bcnt, int E, int NB) {
  __shared__ unsigned hist[800];
  __shared__ unsigned base[800];
  __shared__ unsigned cur[800];
  int t = threadIdx.x;
  for (int i = t; i < NB; i += 256) { hist[i] = 0u; cur[i] = 0u; }
  __syncthreads();

  int chunk = blockIdx.x * 4096;
  int r[16];
#pragma unroll
  for (int i = 0; i < 16; ++i) {
    int e = chunk + i * 256 + t;
    int rr = (e < E) ? ei[e] : -1;
    r[i] = rr;
    if (rr >= 0) atomicAdd(&hist[rr >> 7], 1u);
  }
  __syncthreads();
  for (int i = t; i < NB; i += 256) {
    base[i] = (hist[i] > 0u) ? (unsigned)atomicAdd(&bcnt[i], (int)hist[i]) : 0u;
  }
  __syncthreads();
#pragma unroll
  for (int i = 0; i < 16; ++i) {
    int e = chunk + i * 256 + t;
    if (e < E) {
      int rr = r[i];
      int cc = ei[E + e];                       // source node
      int b = rr >> 7;
      unsigned off = base[b] + atomicAdd(&cur[b], 1u);
      if (off < CAPB)
        part[(size_t)b * CAPB + off] = ((unsigned)cc << 7) | (unsigned)(rr & 127);
    }
  }
}

// K2: per-bucket scatter-max (LDS atomics) + fallback + linear.
__global__ __launch_bounds__(512, 6) void agg_linear_kernel(
    const float* __restrict__ x, const unsigned* __restrict__ part,
    const int* __restrict__ bcnt, const float* __restrict__ W,
    const float* __restrict__ bias, float* __restrict__ out, int N) {
  __shared__ unsigned tile[BN * TS];   // 33280 B; float-reused after decode
  __shared__ float Wt[64 * 68];        // 17408 B; Wt[k*68+o] = W[o][k]
  float* tilef = (float*)tile;

  int t = threadIdx.x;
  int w = t >> 6, lane = t & 63;
  int m16 = lane & 15, g = lane >> 4;  // 16-lane group id 0..3

  for (int i = t; i < BN * TS; i += 512) tile[i] = SENT;
  for (int idx = t; idx < 4096; idx += 512) {
    int o = idx >> 6, k = idx & 63;
    Wt[k * 68 + o] = W[idx];
  }
  __syncthreads();

  int b = blockIdx.x;
  int cnt = bcnt[b];
  if (cnt > CAPB) cnt = CAPB;
  const unsigned* ebase = part + (size_t)b * CAPB;

  // Edge phase: wave takes 64-edge chunks. Fast path (full chunk): 4
  // macro-steps; each issues 4 dwordx4 gathers (16 edges, 4KB in flight),
  // then 16 LDS atomicMax (4/lane; each instr covers 4 edges x 16 dims).
  for (int e0 = w * 64; e0 < cnt; e0 += 512) {
    int idx = e0 + lane;
    unsigned pk = (idx < cnt) ? ebase[idx] : 0u;
    int nv = cnt - e0; if (nv > 64) nv = 64;
    if (nv == 64) {
#pragma unroll
      for (int ms = 0; ms < 4; ++ms) {
        unsigned p[4]; float4 v[4];
#pragma unroll
        for (int q = 0; q < 4; ++q) {
          p[q] = __shfl(pk, ms * 16 + q * 4 + g);
          v[q] = *reinterpret_cast<const float4*>(
                     &x[(size_t)(p[q] >> 7) * 64 + 4 * m16]);
        }
#pragma unroll
        for (int q = 0; q < 4; ++q) {
          unsigned rb = (p[q] & 127u) * TS + 4 * m16;
          atomicMax(&tile[rb + 0], encf(v[q].x));
          atomicMax(&tile[rb + 1], encf(v[q].y));
          atomicMax(&tile[rb + 2], encf(v[q].z));
          atomicMax(&tile[rb + 3], encf(v[q].w));
        }
      }
    } else {
      // tail: old guarded per-edge path (lane = dim)
      for (int j0 = 0; j0 < nv; j0 += 8) {
        unsigned p[8]; float v[8];
#pragma unroll
        for (int jj = 0; jj < 8; ++jj) p[jj] = __shfl(pk, j0 + jj);
#pragma unroll
        for (int jj = 0; jj < 8; ++jj)
          if (j0 + jj < nv) v[jj] = x[(size_t)(p[jj] >> 7) * 64 + lane];
#pragma unroll
        for (int jj = 0; jj < 8; ++jj)
          if (j0 + jj < nv)
            atomicMax(&tile[(p[jj] & 127u) * TS + lane], encf(v[jj]));
      }
    }
  }
  __syncthreads();

  // Fallback + decode in place (each wave owns 16 rows; lane RMWs own slot).
  int basen = b * BN;
#pragma unroll 4
  for (int i = 0; i < 16; ++i) {
    int row = w * 16 + i;
    int node = basen + row;
    unsigned u0 = tile[row * TS];          // broadcast read, dim 0
    unsigned ul = tile[row * TS + lane];
    float val;
    if (u0 == SENT) val = (node < N) ? x[(size_t)node * 64 + lane] : 0.f;
    else            val = decf(ul);
    tilef[row * TS + lane] = val;
  }
  __syncthreads();

  // Linear: out[128 nodes][64 outs] = tile @ W^T + b, 4x4 microtile.
  int to = t & 15;    // output cols 4*to..+3
  int tn = t >> 4;    // local rows 4*tn..+3 (0..31)

  float acc[4][4];
#pragma unroll
  for (int i = 0; i < 4; ++i)
#pragma unroll
    for (int j = 0; j < 4; ++j) acc[i][j] = 0.f;

#pragma unroll 4
  for (int k = 0; k < 64; ++k) {
    float4 wq = *reinterpret_cast<const float4*>(&Wt[k * 68 + 4 * to]);
    float wv[4] = {wq.x, wq.y, wq.z, wq.w};
#pragma unroll
    for (int i = 0; i < 4; ++i) {
      float a = tilef[(4 * tn + i) * TS + k];
#pragma unroll
      for (int j = 0; j < 4; ++j) acc[i][j] += a * wv[j];
    }
  }

  float4 bq = *reinterpret_cast<const float4*>(&bias[4 * to]);
  float bv[4] = {bq.x, bq.y, bq.z, bq.w};
#pragma unroll
  for (int i = 0; i < 4; ++i) {
    int node = basen + 4 * tn + i;
    if (node < N) {
      float4 r;
      r.x = acc[i][0] + bv[0];
      r.y = acc[i][1] + bv[1];
      r.z = acc[i][2] + bv[2];
      r.w = acc[i][3] + bv[3];
      *reinterpret_cast<float4*>(&out[(size_t)node * 64 + 4 * to]) = r;
    }
  }
}

extern "C" void kernel_launch(void* const* d_in, const int* in_sizes, int n_in,
                              void* d_out, int out_size, void* d_ws, size_t ws_size,
                              hipStream_t stream) {
  const float* x    = (const float*)d_in[0];
  const float* W    = (const float*)d_in[1];
  const float* bias = (const float*)d_in[2];
  const int*   ei   = (const int*)d_in[3];
  float* out = (float*)d_out;

  int N = in_sizes[0] / 64;   // 100000
  int E = in_sizes[3] / 2;    // 1600000
  int NB = (N + BN - 1) / BN; // 782 buckets

  // Workspace: part NB*CAPB u32 (7.6MB) + bcnt NB ints
  char* ws = (char*)d_ws;
  unsigned* part = (unsigned*)ws;
  int* bcnt = (int*)(ws + (size_t)NB * CAPB * 4);

  hipMemsetAsync(bcnt, 0, (size_t)NB * 4, stream);

  {
    int blocks = (E + 4095) / 4096;
    partition_kernel<<<blocks, 256, 0, stream>>>(ei, part, bcnt, E, NB);
  }
  {
    agg_linear_kernel<<<NB, 512, 0, stream>>>(x, part, bcnt, W, bias, out, N);
  }
}